// Round 6
// baseline (584.365 us; speedup 1.0000x reference)
//
#include <hip/hip_runtime.h>
#include <math.h>

typedef _Float16 f16;
typedef _Float16 h8  __attribute__((ext_vector_type(8)));
typedef _Float16 h4  __attribute__((ext_vector_type(4)));
typedef _Float16 h2v __attribute__((ext_vector_type(2)));
typedef float    f4  __attribute__((ext_vector_type(4)));

#define N_NODES 100000
#define N_EDGES 1600000
#define FDIM    128
#define CDIM    20
#define NEG_SLOPE 0.01f

#define NPART 782                    // partitions of 128 dst nodes
#define NB    256                    // histogram/scatter blocks
#define EPB   (N_EDGES / NB)         // 6250 edges per block
#define PBUF  2944                   // repack LDS capacity (mean 2046, +20 sigma)
#define GATHER_BLOCKS (N_NODES * 32 / 256)   // 12500

// ---------------------------------------------------------------------------
// K1: blocks [0,NB) build per-block dst-partition histograms (LDS atomics,
// zero global atomics); remaining blocks gather emb rows fp32->fp16.
// Every histG entry is written -> no memset needed anywhere.
// ---------------------------------------------------------------------------
__global__ __launch_bounds__(256) void k1_hist_gather(const int* __restrict__ ids,
                                                      const float* __restrict__ emb,
                                                      f16* __restrict__ X,
                                                      const int* __restrict__ dst,
                                                      int* __restrict__ histG) {
    int b = blockIdx.x, t = threadIdx.x;
    if (b < NB) {
        __shared__ unsigned lh[NPART];
        for (int i = t; i < NPART; i += 256) lh[i] = 0;
        __syncthreads();
        int e0 = b * EPB;
        for (int i = t; i < EPB; i += 256)
            atomicAdd(&lh[dst[e0 + i] >> 7], 1u);
        __syncthreads();
        for (int i = t; i < NPART; i += 256) histG[b * NPART + i] = (int)lh[i];
    } else {
        int gid = (b - NB) * 256 + t;                 // N*32 exact
        int n = gid >> 5, qq = gid & 31;
        int v = ids[n];
        float4 vv = ((const float4*)emb)[(size_t)v * 32 + qq];
        h4 o; o[0] = (f16)vv.x; o[1] = (f16)vv.y; o[2] = (f16)vv.z; o[3] = (f16)vv.w;
        ((h4*)X)[(size_t)n * 32 + qq] = o;
    }
}

// ---------------------------------------------------------------------------
// K2: single block. Column totals -> exclusive scan over partitions
// (pstart, exact: sums to E) -> per-(block,partition) offsets in histG.
// ---------------------------------------------------------------------------
__global__ __launch_bounds__(1024) void k2_scan(int* __restrict__ histG,
                                                int* __restrict__ pstart) {
    __shared__ int tot[NPART];
    int t = threadIdx.x;
    if (t < NPART) {
        int s = 0;
        for (int b = 0; b < NB; ++b) s += histG[b * NPART + t];
        tot[t] = s;
    }
    __syncthreads();
    if (t == 0) {
        int run = 0;
        for (int p = 0; p < NPART; ++p) { int v = tot[p]; tot[p] = run; pstart[p] = run; run += v; }
        pstart[NPART] = run;
    }
    __syncthreads();
    if (t < NPART) {
        int run = tot[t];
        for (int b = 0; b < NB; ++b) { int v = histG[b * NPART + t]; histG[b * NPART + t] = run; run += v; }
    }
}

// ---------------------------------------------------------------------------
// K3: deterministic scatter. LDS cursors seeded from exact offsets; records
// land in dense CSR order (runs of ~8 per (block,partition) -> coalesced-ish).
//   rec = ((dl<<17)|src, ew_f32)
// ---------------------------------------------------------------------------
__global__ __launch_bounds__(256) void k3_scatter(const int* __restrict__ src,
                                                  const int* __restrict__ dst,
                                                  const float* __restrict__ ew,
                                                  const int* __restrict__ histG,
                                                  uint2* __restrict__ recs) {
    __shared__ unsigned cur[NPART];
    int b = blockIdx.x, t = threadIdx.x;
    for (int i = t; i < NPART; i += 256) cur[i] = (unsigned)histG[b * NPART + i];
    __syncthreads();
    int e0 = b * EPB;
    for (int i = t; i < EPB; i += 256) {
        int e = e0 + i;
        int s = src[e], d = dst[e];
        int p = d >> 7, dl = d & 127;
        unsigned pos = atomicAdd(&cur[p], 1u);        // LDS atomic only
        uint2 r; r.x = ((unsigned)dl << 17) | (unsigned)s; r.y = __float_as_uint(ew[e]);
        recs[pos] = r;
    }
}

// ---------------------------------------------------------------------------
// K4: per-partition repack (proven R4 pattern): sort records by dst_local
// in LDS, emit nstart/ncnt, weighted degree -> dinv. Strips dl from rec.x.
// ---------------------------------------------------------------------------
__global__ __launch_bounds__(256) void k4_repack(uint2* __restrict__ recs,
                                                 const int* __restrict__ pstart,
                                                 int* __restrict__ nstart,
                                                 int* __restrict__ ncnt,
                                                 float* __restrict__ dinv) {
    __shared__ uint2    buf[PBUF];                    // 23.5 KB
    __shared__ float    wsum[128];
    __shared__ unsigned hcnt[128], pref[128], cur[128];
    int p = blockIdx.x, t = threadIdx.x;
    if (t < 128) { hcnt[t] = 0; wsum[t] = 0.f; }
    __syncthreads();
    int base = pstart[p];
    int c = pstart[p + 1] - base;
    if (c > PBUF) c = PBUF;                           // ~20-sigma guard
    for (int i = t; i < c; i += 256) {
        uint2 r = recs[base + i];
        buf[i] = r;
        int dl = r.x >> 17;
        atomicAdd(&hcnt[dl], 1u);
        atomicAdd(&wsum[dl], __uint_as_float(r.y));
    }
    __syncthreads();
    if (t == 0) {
        unsigned s = 0;
        for (int k = 0; k < 128; ++k) { pref[k] = s; s += hcnt[k]; }
    }
    __syncthreads();
    if (t < 128) {
        cur[t] = pref[t];
        int g = p * 128 + t;
        if (g < N_NODES) {
            nstart[g] = base + (int)pref[t];
            ncnt[g]   = (int)hcnt[t];
            dinv[g]   = rsqrtf(wsum[t] + 1.0f);
        }
    }
    __syncthreads();
    for (int i = t; i < c; i += 256) {
        uint2 r = buf[i];
        int dl = r.x >> 17;
        unsigned pos = atomicAdd(&cur[dl], 1u);
        uint2 o; o.x = r.x & 0x1FFFFu; o.y = r.y;     // strip dl
        recs[base + pos] = o;
    }
}

// ---------------------------------------------------------------------------
// K5: rec.y = dinv[src] * ew  (exact fp32 coef; aggs need no dinv gather)
// ---------------------------------------------------------------------------
__global__ __launch_bounds__(256) void k5_coef(uint2* __restrict__ recs,
                                               const float* __restrict__ dinv) {
    int i = blockIdx.x * 256 + threadIdx.x;
    if (i >= N_EDGES) return;
    uint2 r = recs[i];
    r.y = __float_as_uint(dinv[r.x] * __uint_as_float(r.y));
    recs[i] = r;
}

// ---------------------------------------------------------------------------
// Transpose + fp16-convert W (128x128): WT[n*128+k] = W[k*128+n]
// ---------------------------------------------------------------------------
__global__ __launch_bounds__(256) void prepW(const float* __restrict__ W0,
                                             const float* __restrict__ W1,
                                             f16* __restrict__ W0T,
                                             f16* __restrict__ W1T) {
    int o = blockIdx.x * 256 + threadIdx.x;           // 32768 total
    const float* W = (o < 16384) ? W0 : W1;
    f16* T = (o < 16384) ? W0T : W1T;
    int o2 = o & 16383;
    int n = o2 >> 7, k = o2 & 127;
    T[o2] = (f16)W[k * 128 + n];
}

// ---------------------------------------------------------------------------
// aggK: z[n] = dn*(sum coef*x[s]) + dn^2*x[n]   — wave per node, CSR records
// ---------------------------------------------------------------------------
__global__ __launch_bounds__(256) void aggK(const f16* __restrict__ Xi,
                                            const float* __restrict__ dinv,
                                            const int* __restrict__ nstart,
                                            const int* __restrict__ ncnt,
                                            const uint2* __restrict__ recs,
                                            f16* __restrict__ Zo) {
    int wave = threadIdx.x >> 6, lane = threadIdx.x & 63;
    int node = blockIdx.x * 4 + wave;                 // N/4 blocks exact
    const h2v* H2 = (const h2v*)Xi;
    int st = nstart[node], c = ncnt[node];
    float ax = 0.f, ay = 0.f;
    #pragma unroll 4
    for (int j = 0; j < c; ++j) {
        uint2 r = recs[st + j];                       // uniform broadcast load
        float cc = __uint_as_float(r.y);
        h2v hh = H2[(size_t)r.x * 64 + lane];
        ax += cc * (float)hh[0];
        ay += cc * (float)hh[1];
    }
    float dn = dinv[node], d2 = dn * dn;
    h2v hv = H2[(size_t)node * 64 + lane];
    ax = dn * ax + d2 * (float)hv[0];
    ay = dn * ay + d2 * (float)hv[1];
    h2v o; o[0] = (f16)ax; o[1] = (f16)ay;
    ((h2v*)Zo)[(size_t)node * 64 + lane] = o;
}

// ---------------------------------------------------------------------------
// gemmF: X = leaky(Z @ W + b), fp16 MFMA 16x16x32; 64 rows/block, 4 waves.
// ---------------------------------------------------------------------------
#define GP 136
__global__ __launch_bounds__(256) void gemmF(const f16* __restrict__ Z,
                                             const f16* __restrict__ WT,
                                             const float* __restrict__ bias,
                                             f16* __restrict__ X,
                                             int nrows) {
    __shared__ f16 Xs[64 * GP];
    __shared__ f16 Ws[128 * GP];
    __shared__ float Lb[128];
    int t = threadIdx.x;
    size_t rbase = (size_t)blockIdx.x * 64;

    #pragma unroll
    for (int i = 0; i < 4; ++i) {
        int c = t + 256 * i; int r = c >> 4, c8 = c & 15;
        h8 val = {};
        if (rbase + r < (size_t)nrows)
            val = *(const h8*)(Z + (rbase + r) * 128 + c8 * 8);
        *(h8*)(Xs + r * GP + c8 * 8) = val;
    }
    #pragma unroll
    for (int i = 0; i < 8; ++i) {
        int c = t + 256 * i; int nn = c >> 4, c8 = c & 15;
        *(h8*)(Ws + nn * GP + c8 * 8) = *(const h8*)(WT + nn * 128 + c8 * 8);
    }
    if (t < 128) Lb[t] = bias[t];
    __syncthreads();

    int wave = t >> 6, lane = t & 63, quad = lane >> 4, l15 = lane & 15;
    int m0 = wave * 16;
    f4 acc[8];
    f4 zero = {0.f, 0.f, 0.f, 0.f};
    #pragma unroll
    for (int i = 0; i < 8; ++i) acc[i] = zero;

    #pragma unroll
    for (int kk = 0; kk < 128; kk += 32) {
        h8 a = *(h8*)(Xs + (m0 + l15) * GP + kk + quad * 8);
        #pragma unroll
        for (int nt = 0; nt < 8; ++nt) {
            h8 bf = *(h8*)(Ws + (nt * 16 + l15) * GP + kk + quad * 8);
            acc[nt] = __builtin_amdgcn_mfma_f32_16x16x32_f16(a, bf, acc[nt], 0, 0, 0);
        }
    }
    #pragma unroll
    for (int nt = 0; nt < 8; ++nt) {
        float bb = Lb[nt * 16 + l15];
        #pragma unroll
        for (int r = 0; r < 4; ++r) {
            size_t row = rbase + m0 + quad * 4 + r;
            if (row < (size_t)nrows) {
                float v = acc[nt][r] + bb;
                v = v > 0.f ? v : NEG_SLOPE * v;
                X[row * 128 + nt * 16 + l15] = (f16)v;
            }
        }
    }
}

// ---------------------------------------------------------------------------
// gemm20n: Y = X @ W2 (128 -> 20), fp16 in/out, NO bias (added post-agg)
// ---------------------------------------------------------------------------
__global__ __launch_bounds__(256) void gemm20n(const f16* __restrict__ X,
                                               const float* __restrict__ W2,
                                               f16* __restrict__ Y) {
    __shared__ f16   Xs[32 * 128];
    __shared__ float Ws[128 * CDIM];
    int t = threadIdx.x;
    const h8* X8 = (const h8*)(X + (size_t)blockIdx.x * 32 * 128);
    ((h8*)Xs)[t]       = X8[t];
    ((h8*)Xs)[t + 256] = X8[t + 256];
    for (int i = t; i < 128 * CDIM; i += 256) Ws[i] = W2[i];
    __syncthreads();
    for (int idx = t; idx < 32 * CDIM; idx += 256) {
        int r = idx / CDIM, cc = idx % CDIM;
        float acc = 0.f;
        #pragma unroll 8
        for (int k = 0; k < 128; ++k) acc += (float)Xs[r * 128 + k] * Ws[k * CDIM + cc];
        Y[(size_t)(blockIdx.x * 32 + r) * CDIM + cc] = (f16)acc;
    }
}

// ---------------------------------------------------------------------------
// agg20L: out = LSM( b2 + dn*sum(coef*Y[s]) + dn^2*Y[n] ) — 40B/edge gather
// ---------------------------------------------------------------------------
__global__ __launch_bounds__(256) void agg20L(const f16* __restrict__ Y,
                                              const float* __restrict__ dinv,
                                              const int* __restrict__ nstart,
                                              const int* __restrict__ ncnt,
                                              const uint2* __restrict__ recs,
                                              const float* __restrict__ b2,
                                              float* __restrict__ out) {
    int wave = threadIdx.x >> 6, lane = threadIdx.x & 63;
    int node = blockIdx.x * 4 + wave;
    int st = nstart[node], c = ncnt[node];
    float tv = 0.f;
    #pragma unroll 4
    for (int j = 0; j < c; ++j) {
        uint2 r = recs[st + j];
        float cc = __uint_as_float(r.y);
        if (lane < CDIM) tv += cc * (float)Y[(size_t)r.x * CDIM + lane];
    }
    float dn = dinv[node], d2 = dn * dn;
    if (lane < CDIM)
        tv = b2[lane] + dn * tv + d2 * (float)Y[(size_t)node * CDIM + lane];

    float m = (lane < CDIM) ? tv : -INFINITY;
    #pragma unroll
    for (int off = 16; off >= 1; off >>= 1) m = fmaxf(m, __shfl_down(m, off));
    m = __shfl(m, 0);
    float ex = (lane < CDIM) ? expf(tv - m) : 0.f;
    #pragma unroll
    for (int off = 16; off >= 1; off >>= 1) ex += __shfl_down(ex, off);
    float ssum = __shfl(ex, 0);
    float ls = logf(ssum);
    if (lane < CDIM) out[(size_t)node * CDIM + lane] = tv - m - ls;
}

// ---------------------------------------------------------------------------
extern "C" void kernel_launch(void* const* d_in, const int* in_sizes, int n_in,
                              void* d_out, int out_size, void* d_ws, size_t ws_size,
                              hipStream_t stream) {
    (void)in_sizes; (void)n_in; (void)out_size; (void)ws_size;
    const int*   node_ids = (const int*)d_in[0];
    const int*   e_src    = (const int*)d_in[1];
    const int*   e_dst    = e_src + N_EDGES;
    const float* edge_w   = (const float*)d_in[2];
    const float* emb      = (const float*)d_in[3];
    const float* W0       = (const float*)d_in[4];
    const float* b0       = (const float*)d_in[5];
    const float* W1       = (const float*)d_in[6];
    const float* b1       = (const float*)d_in[7];
    const float* W2       = (const float*)d_in[8];
    const float* b2       = (const float*)d_in[9];
    float* out = (float*)d_out;

    char* w = (char*)d_ws;
    size_t off = 0;
    auto alloc = [&](size_t bytes) {
        void* p = w + off;
        off = (off + bytes + 255) & ~(size_t)255;
        return p;
    };
    f16*   xA     = (f16*)alloc((size_t)N_NODES * FDIM * 2);     // 25.6 MB
    f16*   xB     = (f16*)alloc((size_t)N_NODES * FDIM * 2);     // 25.6 MB
    f16*   ybuf   = xB;                                          // alias (xB free)
    int*   histG  = (int*)alloc((size_t)NB * NPART * 4);         // 800 KB
    int*   pstart = (int*)alloc((size_t)(NPART + 1) * 4);
    int*   nstart = (int*)alloc((size_t)N_NODES * 4);
    int*   ncnt   = (int*)alloc((size_t)N_NODES * 4);
    float* dinv   = (float*)alloc((size_t)N_NODES * 4);
    f16*   W0T    = (f16*)alloc(16384 * 2);
    f16*   W1T    = (f16*)alloc(16384 * 2);
    uint2* recs   = (uint2*)alloc((size_t)N_EDGES * 8);          // 12.8 MB

    prepW<<<128, 256, 0, stream>>>(W0, W1, W0T, W1T);
    k1_hist_gather<<<NB + GATHER_BLOCKS, 256, 0, stream>>>(node_ids, emb, xA, e_dst, histG);
    k2_scan  <<<1, 1024, 0, stream>>>(histG, pstart);
    k3_scatter<<<NB, 256, 0, stream>>>(e_src, e_dst, edge_w, histG, recs);
    k4_repack<<<NPART, 256, 0, stream>>>(recs, pstart, nstart, ncnt, dinv);
    k5_coef  <<<(N_EDGES + 255) / 256, 256, 0, stream>>>(recs, dinv);

    int gblocks = (N_NODES + 63) / 64;
    // layer 0:  z = A.x0 ; x1 = leaky(z W0 + b0)
    aggK <<<N_NODES / 4, 256, 0, stream>>>(xA, dinv, nstart, ncnt, recs, xB);
    gemmF<<<gblocks, 256, 0, stream>>>(xB, W0T, b0, xA, N_NODES);
    // layer 1
    aggK <<<N_NODES / 4, 256, 0, stream>>>(xA, dinv, nstart, ncnt, recs, xB);
    gemmF<<<gblocks, 256, 0, stream>>>(xB, W1T, b1, xA, N_NODES);
    // layer 2:  y = x2 W2 ; out = LSM(A.y + b2)   (aggregate-last: 40B rows)
    gemm20n<<<N_NODES / 32, 256, 0, stream>>>(xA, W2, ybuf);
    agg20L <<<N_NODES / 4, 256, 0, stream>>>(ybuf, dinv, nstart, ncnt, recs, b2, out);
}

// Round 7
// 490.464 us; speedup vs baseline: 1.1915x; 1.1915x over previous
//
#include <hip/hip_runtime.h>
#include <math.h>

typedef _Float16 f16;
typedef _Float16 h8  __attribute__((ext_vector_type(8)));
typedef _Float16 h4  __attribute__((ext_vector_type(4)));
typedef _Float16 h2v __attribute__((ext_vector_type(2)));
typedef float    f4  __attribute__((ext_vector_type(4)));

#define N_NODES 100000
#define N_EDGES 1600000
#define FDIM    128
#define CDIM    20
#define NEG_SLOPE 0.01f

#define NPART 782                    // partitions of 128 dst nodes
#define NB    256                    // histogram/scatter blocks
#define EPB   (N_EDGES / NB)         // 6250 edges per block
#define PBUF  2944                   // repack LDS capacity (mean 2046, +20 sigma)
#define GATHER_BLOCKS (N_NODES * 32 / 256)   // 12500

// ---------------------------------------------------------------------------
// K1: blocks [0,NB) build per-block dst-partition histograms (LDS atomics);
// remaining blocks gather emb rows fp32->fp16.
// ---------------------------------------------------------------------------
__global__ __launch_bounds__(256) void k1_hist_gather(const int* __restrict__ ids,
                                                      const float* __restrict__ emb,
                                                      f16* __restrict__ X,
                                                      const int* __restrict__ dst,
                                                      int* __restrict__ histG) {
    int b = blockIdx.x, t = threadIdx.x;
    if (b < NB) {
        __shared__ unsigned lh[NPART];
        for (int i = t; i < NPART; i += 256) lh[i] = 0;
        __syncthreads();
        int e0 = b * EPB;
        for (int i = t; i < EPB; i += 256)
            atomicAdd(&lh[dst[e0 + i] >> 7], 1u);
        __syncthreads();
        for (int i = t; i < NPART; i += 256) histG[b * NPART + i] = (int)lh[i];
    } else {
        int gid = (b - NB) * 256 + t;                 // N*32 exact
        int n = gid >> 5, qq = gid & 31;
        int v = ids[n];
        float4 vv = ((const float4*)emb)[(size_t)v * 32 + qq];
        h4 o; o[0] = (f16)vv.x; o[1] = (f16)vv.y; o[2] = (f16)vv.z; o[3] = (f16)vv.w;
        ((h4*)X)[(size_t)n * 32 + qq] = o;
    }
}

// ---------------------------------------------------------------------------
// K2a: one block: column totals (independent, pipelined loads) + LDS
// Hillis-Steele scan -> pstart[0..NPART].
// ---------------------------------------------------------------------------
__global__ __launch_bounds__(1024) void k2a_scan(const int* __restrict__ histG,
                                                 int* __restrict__ pstart) {
    __shared__ int a[1024], bb[1024];
    int t = threadIdx.x;
    int s = 0;
    if (t < NPART)
        for (int b = 0; b < NB; ++b) s += histG[b * NPART + t];
    a[t] = s;
    __syncthreads();
    int* cur = a; int* nxt = bb;
    for (int off = 1; off < 1024; off <<= 1) {
        int v = cur[t] + ((t >= off) ? cur[t - off] : 0);
        nxt[t] = v;
        __syncthreads();
        int* tmp = cur; cur = nxt; nxt = tmp;
    }
    if (t < NPART) pstart[t] = cur[t] - s;            // exclusive
    if (t == NPART - 1) pstart[NPART] = cur[t];
}

// ---------------------------------------------------------------------------
// K2b: one wave per partition: scan the 256 per-block counts -> seed offsets
// (replaces a 256-long serial dependent-load chain per thread).
// ---------------------------------------------------------------------------
__global__ __launch_bounds__(256) void k2b_seed(int* __restrict__ histG,
                                                const int* __restrict__ pstart) {
    int w = blockIdx.x * 4 + (threadIdx.x >> 6);
    if (w >= NPART) return;
    int lane = threadIdx.x & 63;
    int base = pstart[w];
    int v[4], pre[4], s = 0;
    #pragma unroll
    for (int i = 0; i < 4; ++i) v[i] = histG[(lane * 4 + i) * NPART + w];
    #pragma unroll
    for (int i = 0; i < 4; ++i) { pre[i] = s; s += v[i]; }
    int ss = s;
    #pragma unroll
    for (int off = 1; off < 64; off <<= 1) {
        int u = __shfl_up(ss, off);
        if (lane >= off) ss += u;
    }
    int wexcl = ss - s;
    #pragma unroll
    for (int i = 0; i < 4; ++i)
        histG[(lane * 4 + i) * NPART + w] = base + wexcl + pre[i];
}

// ---------------------------------------------------------------------------
// K3: deterministic scatter via LDS cursors seeded from exact offsets.
//   rec = ((dl<<17)|src, ew_f32)
// ---------------------------------------------------------------------------
__global__ __launch_bounds__(256) void k3_scatter(const int* __restrict__ src,
                                                  const int* __restrict__ dst,
                                                  const float* __restrict__ ew,
                                                  const int* __restrict__ histG,
                                                  uint2* __restrict__ recs) {
    __shared__ unsigned cur[NPART];
    int b = blockIdx.x, t = threadIdx.x;
    for (int i = t; i < NPART; i += 256) cur[i] = (unsigned)histG[b * NPART + i];
    __syncthreads();
    int e0 = b * EPB;
    for (int i = t; i < EPB; i += 256) {
        int e = e0 + i;
        int s = src[e], d = dst[e];
        int p = d >> 7, dl = d & 127;
        unsigned pos = atomicAdd(&cur[p], 1u);        // LDS atomic only
        uint2 r; r.x = ((unsigned)dl << 17) | (unsigned)s; r.y = __float_as_uint(ew[e]);
        recs[pos] = r;
    }
}

// ---------------------------------------------------------------------------
// K4: per-partition repack: sort records by dst_local in LDS, emit
// nstart/ncnt, weighted degree -> dinv. Strips dl from rec.x.
// ---------------------------------------------------------------------------
__global__ __launch_bounds__(256) void k4_repack(uint2* __restrict__ recs,
                                                 const int* __restrict__ pstart,
                                                 int* __restrict__ nstart,
                                                 int* __restrict__ ncnt,
                                                 float* __restrict__ dinv) {
    __shared__ uint2    buf[PBUF];                    // 23.5 KB
    __shared__ float    wsum[128];
    __shared__ unsigned hcnt[128], pref[128], cur[128];
    int p = blockIdx.x, t = threadIdx.x;
    if (t < 128) { hcnt[t] = 0; wsum[t] = 0.f; }
    __syncthreads();
    int base = pstart[p];
    int c = pstart[p + 1] - base;
    if (c > PBUF) c = PBUF;
    for (int i = t; i < c; i += 256) {
        uint2 r = recs[base + i];
        buf[i] = r;
        int dl = r.x >> 17;
        atomicAdd(&hcnt[dl], 1u);
        atomicAdd(&wsum[dl], __uint_as_float(r.y));
    }
    __syncthreads();
    if (t == 0) {
        unsigned s = 0;
        for (int k = 0; k < 128; ++k) { pref[k] = s; s += hcnt[k]; }
    }
    __syncthreads();
    if (t < 128) {
        cur[t] = pref[t];
        int g = p * 128 + t;
        if (g < N_NODES) {
            nstart[g] = base + (int)pref[t];
            ncnt[g]   = (int)hcnt[t];
            dinv[g]   = rsqrtf(wsum[t] + 1.0f);
        }
    }
    __syncthreads();
    for (int i = t; i < c; i += 256) {
        uint2 r = buf[i];
        int dl = r.x >> 17;
        unsigned pos = atomicAdd(&cur[dl], 1u);
        uint2 o; o.x = r.x & 0x1FFFFu; o.y = r.y;
        recs[base + pos] = o;
    }
}

// ---------------------------------------------------------------------------
// K5: rec.y = dinv[src] * ew
// ---------------------------------------------------------------------------
__global__ __launch_bounds__(256) void k5_coef(uint2* __restrict__ recs,
                                               const float* __restrict__ dinv) {
    int i = blockIdx.x * 256 + threadIdx.x;
    if (i >= N_EDGES) return;
    uint2 r = recs[i];
    r.y = __float_as_uint(dinv[r.x] * __uint_as_float(r.y));
    recs[i] = r;
}

// ---------------------------------------------------------------------------
// prepW: WT[n*128+k] = W[k*128+n], fp16
// ---------------------------------------------------------------------------
__global__ __launch_bounds__(256) void prepW(const float* __restrict__ W0,
                                             const float* __restrict__ W1,
                                             f16* __restrict__ W0T,
                                             f16* __restrict__ W1T) {
    int o = blockIdx.x * 256 + threadIdx.x;           // 32768 total
    const float* W = (o < 16384) ? W0 : W1;
    f16* T = (o < 16384) ? W0T : W1T;
    int o2 = o & 16383;
    int n = o2 >> 7, k = o2 & 127;
    T[o2] = (f16)W[k * 128 + n];
}

// ---------------------------------------------------------------------------
// aggK: z[n] = dn*(sum coef*x[s]) + dn^2*x[n].  Wave per node, but 4 edges
// in flight: lane-group g (16 lanes) handles edge st+j+g, loading its row as
// h8 (16 lanes x 16B = 256B). Groups cover the SAME feature slice ->
// shfl_xor(16,32) combine at the end. 4x MLP vs the serial walk (R6 evidence:
// aggs latency-bound, 40B and 256B rows both ~140us).
// ---------------------------------------------------------------------------
__global__ __launch_bounds__(256) void aggK(const f16* __restrict__ Xi,
                                            const float* __restrict__ dinv,
                                            const int* __restrict__ nstart,
                                            const int* __restrict__ ncnt,
                                            const uint2* __restrict__ recs,
                                            f16* __restrict__ Zo) {
    int wave = threadIdx.x >> 6, lane = threadIdx.x & 63;
    int g = lane >> 4, l15 = lane & 15;
    int node = blockIdx.x * 4 + wave;                 // N/4 blocks exact
    int st = nstart[node], c = ncnt[node];
    float acc[8];
    #pragma unroll
    for (int k = 0; k < 8; ++k) acc[k] = 0.f;

    #pragma unroll 2
    for (int j = 0; j < c; j += 4) {
        if (j + g < c) {
            uint2 r = recs[st + j + g];               // 4 groups -> one 32B txn
            float cc = __uint_as_float(r.y);
            h8 hh = *(const h8*)(Xi + (size_t)r.x * 128 + l15 * 8);
            #pragma unroll
            for (int k = 0; k < 8; ++k) acc[k] += cc * (float)hh[k];
        }
    }
    #pragma unroll
    for (int k = 0; k < 8; ++k) {
        acc[k] += __shfl_xor(acc[k], 16);
        acc[k] += __shfl_xor(acc[k], 32);
    }
    float dn = dinv[node], d2 = dn * dn;
    h8 hv = *(const h8*)(Xi + (size_t)node * 128 + l15 * 8);
    if (g == 0) {
        h8 o;
        #pragma unroll
        for (int k = 0; k < 8; ++k) o[k] = (f16)(dn * acc[k] + d2 * (float)hv[k]);
        *(h8*)(Zo + (size_t)node * 128 + l15 * 8) = o;
    }
}

// ---------------------------------------------------------------------------
// gemmF: X = leaky(Z @ W + b), fp16 MFMA 16x16x32; 64 rows/block, 4 waves.
// ---------------------------------------------------------------------------
#define GP 136
__global__ __launch_bounds__(256) void gemmF(const f16* __restrict__ Z,
                                             const f16* __restrict__ WT,
                                             const float* __restrict__ bias,
                                             f16* __restrict__ X,
                                             int nrows) {
    __shared__ f16 Xs[64 * GP];
    __shared__ f16 Ws[128 * GP];
    __shared__ float Lb[128];
    int t = threadIdx.x;
    size_t rbase = (size_t)blockIdx.x * 64;

    #pragma unroll
    for (int i = 0; i < 4; ++i) {
        int c = t + 256 * i; int r = c >> 4, c8 = c & 15;
        h8 val = {};
        if (rbase + r < (size_t)nrows)
            val = *(const h8*)(Z + (rbase + r) * 128 + c8 * 8);
        *(h8*)(Xs + r * GP + c8 * 8) = val;
    }
    #pragma unroll
    for (int i = 0; i < 8; ++i) {
        int c = t + 256 * i; int nn = c >> 4, c8 = c & 15;
        *(h8*)(Ws + nn * GP + c8 * 8) = *(const h8*)(WT + nn * 128 + c8 * 8);
    }
    if (t < 128) Lb[t] = bias[t];
    __syncthreads();

    int wave = t >> 6, lane = t & 63, quad = lane >> 4, l15 = lane & 15;
    int m0 = wave * 16;
    f4 acc[8];
    f4 zero = {0.f, 0.f, 0.f, 0.f};
    #pragma unroll
    for (int i = 0; i < 8; ++i) acc[i] = zero;

    #pragma unroll
    for (int kk = 0; kk < 128; kk += 32) {
        h8 a = *(h8*)(Xs + (m0 + l15) * GP + kk + quad * 8);
        #pragma unroll
        for (int nt = 0; nt < 8; ++nt) {
            h8 bf = *(h8*)(Ws + (nt * 16 + l15) * GP + kk + quad * 8);
            acc[nt] = __builtin_amdgcn_mfma_f32_16x16x32_f16(a, bf, acc[nt], 0, 0, 0);
        }
    }
    #pragma unroll
    for (int nt = 0; nt < 8; ++nt) {
        float bb = Lb[nt * 16 + l15];
        #pragma unroll
        for (int r = 0; r < 4; ++r) {
            size_t row = rbase + m0 + quad * 4 + r;
            if (row < (size_t)nrows) {
                float v = acc[nt][r] + bb;
                v = v > 0.f ? v : NEG_SLOPE * v;
                X[row * 128 + nt * 16 + l15] = (f16)v;
            }
        }
    }
}

// ---------------------------------------------------------------------------
// gemm20p: Y = X @ W2 (128 -> 20), fp16 out, PADDED to stride 32 (cols 20..31
// zeroed) so the aggregation can use h2v lane loads.
// ---------------------------------------------------------------------------
__global__ __launch_bounds__(256) void gemm20p(const f16* __restrict__ X,
                                               const float* __restrict__ W2,
                                               f16* __restrict__ Y) {
    __shared__ f16   Xs[32 * 128];
    __shared__ float Ws[128 * CDIM];
    int t = threadIdx.x;
    const h8* X8 = (const h8*)(X + (size_t)blockIdx.x * 32 * 128);
    ((h8*)Xs)[t]       = X8[t];
    ((h8*)Xs)[t + 256] = X8[t + 256];
    for (int i = t; i < 128 * CDIM; i += 256) Ws[i] = W2[i];
    __syncthreads();
    for (int idx = t; idx < 32 * 32; idx += 256) {
        int r = idx >> 5, cc = idx & 31;
        float acc = 0.f;
        if (cc < CDIM) {
            #pragma unroll 8
            for (int k = 0; k < 128; ++k) acc += (float)Xs[r * 128 + k] * Ws[k * CDIM + cc];
        }
        Y[(size_t)(blockIdx.x * 32 + r) * 32 + cc] = (f16)acc;
    }
}

// ---------------------------------------------------------------------------
// agg20L: out = LSM( b2 + dn*sum(coef*Y[s]) + dn^2*Y[n] ).  Same 4-edge
// lane-group scheme: group g = edge st+j+g; lane loads Y pair (2*l15,2*l15+1)
// as h2v (16 lanes x 4B = padded 64B row). xor-combine, then softmax within
// the 16-lane group (pairs 0..9 hold the 20 classes).
// ---------------------------------------------------------------------------
__global__ __launch_bounds__(256) void agg20L(const f16* __restrict__ Y,
                                              const float* __restrict__ dinv,
                                              const int* __restrict__ nstart,
                                              const int* __restrict__ ncnt,
                                              const uint2* __restrict__ recs,
                                              const float* __restrict__ b2,
                                              float* __restrict__ out) {
    int wave = threadIdx.x >> 6, lane = threadIdx.x & 63;
    int g = lane >> 4, l15 = lane & 15;
    int node = blockIdx.x * 4 + wave;
    int st = nstart[node], c = ncnt[node];
    const h2v* Y2 = (const h2v*)Y;
    float bx = 0.f, by = 0.f;
    #pragma unroll 2
    for (int j = 0; j < c; j += 4) {
        if (j + g < c) {
            uint2 r = recs[st + j + g];
            float cc = __uint_as_float(r.y);
            h2v hh = Y2[(size_t)r.x * 16 + l15];
            bx += cc * (float)hh[0];
            by += cc * (float)hh[1];
        }
    }
    bx += __shfl_xor(bx, 16); bx += __shfl_xor(bx, 32);
    by += __shfl_xor(by, 16); by += __shfl_xor(by, 32);

    float dn = dinv[node], d2 = dn * dn;
    h2v hz = Y2[(size_t)node * 16 + l15];
    float tx = 0.f, ty = 0.f;
    bool live = (l15 < 10);                           // pairs 0..9 = 20 classes
    if (live) {
        tx = b2[2 * l15]     + dn * bx + d2 * (float)hz[0];
        ty = b2[2 * l15 + 1] + dn * by + d2 * (float)hz[1];
    }
    float mm = live ? fmaxf(tx, ty) : -INFINITY;
    #pragma unroll
    for (int off = 8; off >= 1; off >>= 1) mm = fmaxf(mm, __shfl_xor(mm, off));
    float ex = live ? (expf(tx - mm) + expf(ty - mm)) : 0.f;
    #pragma unroll
    for (int off = 8; off >= 1; off >>= 1) ex += __shfl_xor(ex, off);
    float ls = logf(ex);
    if (g == 0 && live) {
        float2 o; o.x = tx - mm - ls; o.y = ty - mm - ls;
        *(float2*)(out + (size_t)node * CDIM + 2 * l15) = o;
    }
}

// ---------------------------------------------------------------------------
extern "C" void kernel_launch(void* const* d_in, const int* in_sizes, int n_in,
                              void* d_out, int out_size, void* d_ws, size_t ws_size,
                              hipStream_t stream) {
    (void)in_sizes; (void)n_in; (void)out_size; (void)ws_size;
    const int*   node_ids = (const int*)d_in[0];
    const int*   e_src    = (const int*)d_in[1];
    const int*   e_dst    = e_src + N_EDGES;
    const float* edge_w   = (const float*)d_in[2];
    const float* emb      = (const float*)d_in[3];
    const float* W0       = (const float*)d_in[4];
    const float* b0       = (const float*)d_in[5];
    const float* W1       = (const float*)d_in[6];
    const float* b1       = (const float*)d_in[7];
    const float* W2       = (const float*)d_in[8];
    const float* b2       = (const float*)d_in[9];
    float* out = (float*)d_out;

    char* w = (char*)d_ws;
    size_t off = 0;
    auto alloc = [&](size_t bytes) {
        void* p = w + off;
        off = (off + bytes + 255) & ~(size_t)255;
        return p;
    };
    f16*   xA     = (f16*)alloc((size_t)N_NODES * FDIM * 2);     // 25.6 MB
    f16*   xB     = (f16*)alloc((size_t)N_NODES * FDIM * 2);     // 25.6 MB
    f16*   ybuf   = xB;                                          // alias (xB free)
    int*   histG  = (int*)alloc((size_t)NB * NPART * 4);         // 800 KB
    int*   pstart = (int*)alloc((size_t)(NPART + 1) * 4);
    int*   nstart = (int*)alloc((size_t)N_NODES * 4);
    int*   ncnt   = (int*)alloc((size_t)N_NODES * 4);
    float* dinv   = (float*)alloc((size_t)N_NODES * 4);
    f16*   W0T    = (f16*)alloc(16384 * 2);
    f16*   W1T    = (f16*)alloc(16384 * 2);
    uint2* recs   = (uint2*)alloc((size_t)N_EDGES * 8);          // 12.8 MB

    prepW<<<128, 256, 0, stream>>>(W0, W1, W0T, W1T);
    k1_hist_gather<<<NB + GATHER_BLOCKS, 256, 0, stream>>>(node_ids, emb, xA, e_dst, histG);
    k2a_scan<<<1, 1024, 0, stream>>>(histG, pstart);
    k2b_seed<<<(NPART + 3) / 4, 256, 0, stream>>>(histG, pstart);
    k3_scatter<<<NB, 256, 0, stream>>>(e_src, e_dst, edge_w, histG, recs);
    k4_repack<<<NPART, 256, 0, stream>>>(recs, pstart, nstart, ncnt, dinv);
    k5_coef<<<(N_EDGES + 255) / 256, 256, 0, stream>>>(recs, dinv);

    int gblocks = (N_NODES + 63) / 64;
    // layer 0:  z = A.x0 ; x1 = leaky(z W0 + b0)
    aggK <<<N_NODES / 4, 256, 0, stream>>>(xA, dinv, nstart, ncnt, recs, xB);
    gemmF<<<gblocks, 256, 0, stream>>>(xB, W0T, b0, xA, N_NODES);
    // layer 1
    aggK <<<N_NODES / 4, 256, 0, stream>>>(xA, dinv, nstart, ncnt, recs, xB);
    gemmF<<<gblocks, 256, 0, stream>>>(xB, W1T, b1, xA, N_NODES);
    // layer 2:  y = x2 W2 (padded) ; out = LSM(A.y + b2)
    gemm20p<<<N_NODES / 32, 256, 0, stream>>>(xA, W2, ybuf);
    agg20L <<<N_NODES / 4, 256, 0, stream>>>(ybuf, dinv, nstart, ncnt, recs, b2, out);
}

// Round 8
// 460.092 us; speedup vs baseline: 1.2701x; 1.0660x over previous
//
#include <hip/hip_runtime.h>
#include <math.h>

typedef _Float16 f16;
typedef _Float16 h8  __attribute__((ext_vector_type(8)));
typedef _Float16 h4  __attribute__((ext_vector_type(4)));
typedef _Float16 h2v __attribute__((ext_vector_type(2)));
typedef float    f4  __attribute__((ext_vector_type(4)));

#define N_NODES 100000
#define N_EDGES 1600000
#define FDIM    128
#define CDIM    20
#define NEG_SLOPE 0.01f

#define NPART 782                    // partitions of 128 dst nodes
#define NB    256                    // histogram/scatter blocks
#define EPB   (N_EDGES / NB)         // 6250 edges per block
#define PBUF  2944                   // repack LDS capacity (mean 2046, +20 sigma)
#define GATHER_BLOCKS (N_NODES * 32 / 256)   // 12500

// ---------------------------------------------------------------------------
// K1 (fused): [0,NB) per-block dst-partition histograms (LDS atomics);
// [NB, NB+GATHER) emb-row gather fp32->fp16; last 128 blocks transpose W0/W1.
// ---------------------------------------------------------------------------
__global__ __launch_bounds__(256) void k1_build(const int* __restrict__ ids,
                                                const float* __restrict__ emb,
                                                f16* __restrict__ X,
                                                const int* __restrict__ dst,
                                                int* __restrict__ histG,
                                                const float* __restrict__ W0,
                                                const float* __restrict__ W1,
                                                f16* __restrict__ W0T,
                                                f16* __restrict__ W1T) {
    int b = blockIdx.x, t = threadIdx.x;
    if (b < NB) {
        __shared__ unsigned lh[NPART];
        for (int i = t; i < NPART; i += 256) lh[i] = 0;
        __syncthreads();
        int e0 = b * EPB;
        for (int i = t; i < EPB; i += 256)
            atomicAdd(&lh[dst[e0 + i] >> 7], 1u);
        __syncthreads();
        for (int i = t; i < NPART; i += 256) histG[b * NPART + i] = (int)lh[i];
    } else if (b < NB + GATHER_BLOCKS) {
        int gid = (b - NB) * 256 + t;                 // N*32 exact
        int n = gid >> 5, qq = gid & 31;
        int v = ids[n];
        float4 vv = ((const float4*)emb)[(size_t)v * 32 + qq];
        h4 o; o[0] = (f16)vv.x; o[1] = (f16)vv.y; o[2] = (f16)vv.z; o[3] = (f16)vv.w;
        ((h4*)X)[(size_t)n * 32 + qq] = o;
    } else {
        int o = (b - NB - GATHER_BLOCKS) * 256 + t;   // 32768 total
        const float* W = (o < 16384) ? W0 : W1;
        f16* T = (o < 16384) ? W0T : W1T;
        int o2 = o & 16383;
        int n = o2 >> 7, k = o2 & 127;
        T[o2] = (f16)W[k * 128 + n];
    }
}

// ---------------------------------------------------------------------------
// K2a: one block: column totals + LDS Hillis-Steele scan -> pstart[0..NPART].
// ---------------------------------------------------------------------------
__global__ __launch_bounds__(1024) void k2a_scan(const int* __restrict__ histG,
                                                 int* __restrict__ pstart) {
    __shared__ int a[1024], bb[1024];
    int t = threadIdx.x;
    int s = 0;
    if (t < NPART)
        for (int b = 0; b < NB; ++b) s += histG[b * NPART + t];
    a[t] = s;
    __syncthreads();
    int* cur = a; int* nxt = bb;
    for (int off = 1; off < 1024; off <<= 1) {
        int v = cur[t] + ((t >= off) ? cur[t - off] : 0);
        nxt[t] = v;
        __syncthreads();
        int* tmp = cur; cur = nxt; nxt = tmp;
    }
    if (t < NPART) pstart[t] = cur[t] - s;            // exclusive
    if (t == NPART - 1) pstart[NPART] = cur[t];
}

// ---------------------------------------------------------------------------
// K2b: one wave per partition: scan the 256 per-block counts -> seed offsets.
// ---------------------------------------------------------------------------
__global__ __launch_bounds__(256) void k2b_seed(int* __restrict__ histG,
                                                const int* __restrict__ pstart) {
    int w = blockIdx.x * 4 + (threadIdx.x >> 6);
    if (w >= NPART) return;
    int lane = threadIdx.x & 63;
    int base = pstart[w];
    int v[4], pre[4], s = 0;
    #pragma unroll
    for (int i = 0; i < 4; ++i) v[i] = histG[(lane * 4 + i) * NPART + w];
    #pragma unroll
    for (int i = 0; i < 4; ++i) { pre[i] = s; s += v[i]; }
    int ss = s;
    #pragma unroll
    for (int off = 1; off < 64; off <<= 1) {
        int u = __shfl_up(ss, off);
        if (lane >= off) ss += u;
    }
    int wexcl = ss - s;
    #pragma unroll
    for (int i = 0; i < 4; ++i)
        histG[(lane * 4 + i) * NPART + w] = base + wexcl + pre[i];
}

// ---------------------------------------------------------------------------
// K3: deterministic scatter via LDS cursors seeded from exact offsets.
//   rec = ((dl<<17)|src, ew_f32)
// ---------------------------------------------------------------------------
__global__ __launch_bounds__(256) void k3_scatter(const int* __restrict__ src,
                                                  const int* __restrict__ dst,
                                                  const float* __restrict__ ew,
                                                  const int* __restrict__ histG,
                                                  uint2* __restrict__ recs) {
    __shared__ unsigned cur[NPART];
    int b = blockIdx.x, t = threadIdx.x;
    for (int i = t; i < NPART; i += 256) cur[i] = (unsigned)histG[b * NPART + i];
    __syncthreads();
    int e0 = b * EPB;
    for (int i = t; i < EPB; i += 256) {
        int e = e0 + i;
        int s = src[e], d = dst[e];
        int p = d >> 7, dl = d & 127;
        unsigned pos = atomicAdd(&cur[p], 1u);        // LDS atomic only
        uint2 r; r.x = ((unsigned)dl << 17) | (unsigned)s; r.y = __float_as_uint(ew[e]);
        recs[pos] = r;
    }
}

// ---------------------------------------------------------------------------
// K4: per-partition repack: sort records by dst_local in LDS, emit
// nstart/ncnt, weighted degree -> dinv. Strips dl from rec.x.
// ---------------------------------------------------------------------------
__global__ __launch_bounds__(256) void k4_repack(uint2* __restrict__ recs,
                                                 const int* __restrict__ pstart,
                                                 int* __restrict__ nstart,
                                                 int* __restrict__ ncnt,
                                                 float* __restrict__ dinv) {
    __shared__ uint2    buf[PBUF];                    // 23.5 KB
    __shared__ float    wsum[128];
    __shared__ unsigned hcnt[128], pref[128], cur[128];
    int p = blockIdx.x, t = threadIdx.x;
    if (t < 128) { hcnt[t] = 0; wsum[t] = 0.f; }
    __syncthreads();
    int base = pstart[p];
    int c = pstart[p + 1] - base;
    if (c > PBUF) c = PBUF;
    for (int i = t; i < c; i += 256) {
        uint2 r = recs[base + i];
        buf[i] = r;
        int dl = r.x >> 17;
        atomicAdd(&hcnt[dl], 1u);
        atomicAdd(&wsum[dl], __uint_as_float(r.y));
    }
    __syncthreads();
    if (t == 0) {
        unsigned s = 0;
        for (int k = 0; k < 128; ++k) { pref[k] = s; s += hcnt[k]; }
    }
    __syncthreads();
    if (t < 128) {
        cur[t] = pref[t];
        int g = p * 128 + t;
        if (g < N_NODES) {
            nstart[g] = base + (int)pref[t];
            ncnt[g]   = (int)hcnt[t];
            dinv[g]   = rsqrtf(wsum[t] + 1.0f);
        }
    }
    __syncthreads();
    for (int i = t; i < c; i += 256) {
        uint2 r = buf[i];
        int dl = r.x >> 17;
        unsigned pos = atomicAdd(&cur[dl], 1u);
        uint2 o; o.x = r.x & 0x1FFFFu; o.y = r.y;
        recs[base + pos] = o;
    }
}

// ---------------------------------------------------------------------------
// aggK: z[n] = dn*(sum dinv[s]*ew*x[s]) + dn^2*x[n].  Wave per node, 8 edges
// in flight: lane-group g of 8 lanes handles edge st+j+g; lane loads 32B of
// the row (2x h8). coef computed on the fly (dinv is 400KB, L2-resident
// broadcast load, pipelined). xor(8,16,32) combine at the end.
// ---------------------------------------------------------------------------
__global__ __launch_bounds__(256) void aggK(const f16* __restrict__ Xi,
                                            const float* __restrict__ dinv,
                                            const int* __restrict__ nstart,
                                            const int* __restrict__ ncnt,
                                            const uint2* __restrict__ recs,
                                            f16* __restrict__ Zo) {
    int wave = threadIdx.x >> 6, lane = threadIdx.x & 63;
    int g = lane >> 3, l7 = lane & 7;
    int node = blockIdx.x * 4 + wave;                 // N/4 blocks exact
    int st = nstart[node], c = ncnt[node];
    float acc[16];
    #pragma unroll
    for (int k = 0; k < 16; ++k) acc[k] = 0.f;

    for (int j = 0; j < c; j += 8) {
        if (j + g < c) {
            uint2 r = recs[st + j + g];               // broadcast within group
            float cc = dinv[r.x] * __uint_as_float(r.y);
            const f16* rp = Xi + (size_t)r.x * 128 + l7 * 16;
            h8 h0 = *(const h8*)rp;
            h8 h1 = *(const h8*)(rp + 8);
            #pragma unroll
            for (int k = 0; k < 8; ++k) acc[k]     += cc * (float)h0[k];
            #pragma unroll
            for (int k = 0; k < 8; ++k) acc[k + 8] += cc * (float)h1[k];
        }
    }
    #pragma unroll
    for (int k = 0; k < 16; ++k) {
        acc[k] += __shfl_xor(acc[k], 8);
        acc[k] += __shfl_xor(acc[k], 16);
        acc[k] += __shfl_xor(acc[k], 32);
    }
    float dn = dinv[node], d2 = dn * dn;
    const f16* sp = Xi + (size_t)node * 128 + l7 * 16;
    h8 s0 = *(const h8*)sp;
    h8 s1 = *(const h8*)(sp + 8);
    if (g == 0) {
        h8 o0, o1;
        #pragma unroll
        for (int k = 0; k < 8; ++k) o0[k] = (f16)(dn * acc[k]     + d2 * (float)s0[k]);
        #pragma unroll
        for (int k = 0; k < 8; ++k) o1[k] = (f16)(dn * acc[k + 8] + d2 * (float)s1[k]);
        f16* zp = Zo + (size_t)node * 128 + l7 * 16;
        *(h8*)zp = o0;
        *(h8*)(zp + 8) = o1;
    }
}

// ---------------------------------------------------------------------------
// gemmF: X = leaky(Z @ W + b), fp16 MFMA 16x16x32; 64 rows/block, 4 waves.
// ---------------------------------------------------------------------------
#define GP 136
__global__ __launch_bounds__(256) void gemmF(const f16* __restrict__ Z,
                                             const f16* __restrict__ WT,
                                             const float* __restrict__ bias,
                                             f16* __restrict__ X,
                                             int nrows) {
    __shared__ f16 Xs[64 * GP];
    __shared__ f16 Ws[128 * GP];
    __shared__ float Lb[128];
    int t = threadIdx.x;
    size_t rbase = (size_t)blockIdx.x * 64;

    #pragma unroll
    for (int i = 0; i < 4; ++i) {
        int c = t + 256 * i; int r = c >> 4, c8 = c & 15;
        h8 val = {};
        if (rbase + r < (size_t)nrows)
            val = *(const h8*)(Z + (rbase + r) * 128 + c8 * 8);
        *(h8*)(Xs + r * GP + c8 * 8) = val;
    }
    #pragma unroll
    for (int i = 0; i < 8; ++i) {
        int c = t + 256 * i; int nn = c >> 4, c8 = c & 15;
        *(h8*)(Ws + nn * GP + c8 * 8) = *(const h8*)(WT + nn * 128 + c8 * 8);
    }
    if (t < 128) Lb[t] = bias[t];
    __syncthreads();

    int wave = t >> 6, lane = t & 63, quad = lane >> 4, l15 = lane & 15;
    int m0 = wave * 16;
    f4 acc[8];
    f4 zero = {0.f, 0.f, 0.f, 0.f};
    #pragma unroll
    for (int i = 0; i < 8; ++i) acc[i] = zero;

    #pragma unroll
    for (int kk = 0; kk < 128; kk += 32) {
        h8 a = *(h8*)(Xs + (m0 + l15) * GP + kk + quad * 8);
        #pragma unroll
        for (int nt = 0; nt < 8; ++nt) {
            h8 bf = *(h8*)(Ws + (nt * 16 + l15) * GP + kk + quad * 8);
            acc[nt] = __builtin_amdgcn_mfma_f32_16x16x32_f16(a, bf, acc[nt], 0, 0, 0);
        }
    }
    #pragma unroll
    for (int nt = 0; nt < 8; ++nt) {
        float bb = Lb[nt * 16 + l15];
        #pragma unroll
        for (int r = 0; r < 4; ++r) {
            size_t row = rbase + m0 + quad * 4 + r;
            if (row < (size_t)nrows) {
                float v = acc[nt][r] + bb;
                v = v > 0.f ? v : NEG_SLOPE * v;
                X[row * 128 + nt * 16 + l15] = (f16)v;
            }
        }
    }
}

// ---------------------------------------------------------------------------
// gemm20p: Y = X @ W2 (128 -> 20), fp16 out, padded to stride 32.
// ---------------------------------------------------------------------------
__global__ __launch_bounds__(256) void gemm20p(const f16* __restrict__ X,
                                               const float* __restrict__ W2,
                                               f16* __restrict__ Y) {
    __shared__ f16   Xs[32 * 128];
    __shared__ float Ws[128 * CDIM];
    int t = threadIdx.x;
    const h8* X8 = (const h8*)(X + (size_t)blockIdx.x * 32 * 128);
    ((h8*)Xs)[t]       = X8[t];
    ((h8*)Xs)[t + 256] = X8[t + 256];
    for (int i = t; i < 128 * CDIM; i += 256) Ws[i] = W2[i];
    __syncthreads();
    for (int idx = t; idx < 32 * 32; idx += 256) {
        int r = idx >> 5, cc = idx & 31;
        float acc = 0.f;
        if (cc < CDIM) {
            #pragma unroll 8
            for (int k = 0; k < 128; ++k) acc += (float)Xs[r * 128 + k] * Ws[k * CDIM + cc];
        }
        Y[(size_t)(blockIdx.x * 32 + r) * 32 + cc] = (f16)acc;
    }
}

// ---------------------------------------------------------------------------
// agg20L: out = LSM( b2 + dn*sum(dinv[s]*ew*Y[s]) + dn^2*Y[n] ).  8-edge
// lane-group scheme: group g of 8 lanes = edge st+j+g; lane loads h4 of the
// padded 64B row. xor(8,16,32) combine; group-local log-softmax (lanes 0..4
// hold the 20 classes as 4-feature slices).
// ---------------------------------------------------------------------------
__global__ __launch_bounds__(256) void agg20L(const f16* __restrict__ Y,
                                              const float* __restrict__ dinv,
                                              const int* __restrict__ nstart,
                                              const int* __restrict__ ncnt,
                                              const uint2* __restrict__ recs,
                                              const float* __restrict__ b2,
                                              float* __restrict__ out) {
    int wave = threadIdx.x >> 6, lane = threadIdx.x & 63;
    int g = lane >> 3, l7 = lane & 7;
    int node = blockIdx.x * 4 + wave;
    int st = nstart[node], c = ncnt[node];
    float acc[4];
    #pragma unroll
    for (int k = 0; k < 4; ++k) acc[k] = 0.f;

    for (int j = 0; j < c; j += 8) {
        if (j + g < c) {
            uint2 r = recs[st + j + g];
            float cc = dinv[r.x] * __uint_as_float(r.y);
            h4 hh = *(const h4*)(Y + (size_t)r.x * 32 + l7 * 4);
            #pragma unroll
            for (int k = 0; k < 4; ++k) acc[k] += cc * (float)hh[k];
        }
    }
    #pragma unroll
    for (int k = 0; k < 4; ++k) {
        acc[k] += __shfl_xor(acc[k], 8);
        acc[k] += __shfl_xor(acc[k], 16);
        acc[k] += __shfl_xor(acc[k], 32);
    }
    float dn = dinv[node], d2 = dn * dn;
    h4 hz = *(const h4*)(Y + (size_t)node * 32 + l7 * 4);
    bool live = (l7 < 5);                             // 5 lanes x 4 = 20 classes
    float tv[4];
    float mx = -INFINITY;
    #pragma unroll
    for (int k = 0; k < 4; ++k) {
        tv[k] = live ? (b2[l7 * 4 + k] + dn * acc[k] + d2 * (float)hz[k]) : -INFINITY;
        mx = fmaxf(mx, tv[k]);
    }
    #pragma unroll
    for (int off = 1; off <= 4; off <<= 1) mx = fmaxf(mx, __shfl_xor(mx, off));
    float ex = 0.f;
    if (live) {
        #pragma unroll
        for (int k = 0; k < 4; ++k) ex += expf(tv[k] - mx);
    }
    #pragma unroll
    for (int off = 1; off <= 4; off <<= 1) ex += __shfl_xor(ex, off);
    float ls = logf(ex);
    if (g == 0 && live) {
        float4 o;
        o.x = tv[0] - mx - ls; o.y = tv[1] - mx - ls;
        o.z = tv[2] - mx - ls; o.w = tv[3] - mx - ls;
        *(float4*)(out + (size_t)node * CDIM + l7 * 4) = o;
    }
}

// ---------------------------------------------------------------------------
extern "C" void kernel_launch(void* const* d_in, const int* in_sizes, int n_in,
                              void* d_out, int out_size, void* d_ws, size_t ws_size,
                              hipStream_t stream) {
    (void)in_sizes; (void)n_in; (void)out_size; (void)ws_size;
    const int*   node_ids = (const int*)d_in[0];
    const int*   e_src    = (const int*)d_in[1];
    const int*   e_dst    = e_src + N_EDGES;
    const float* edge_w   = (const float*)d_in[2];
    const float* emb      = (const float*)d_in[3];
    const float* W0       = (const float*)d_in[4];
    const float* b0       = (const float*)d_in[5];
    const float* W1       = (const float*)d_in[6];
    const float* b1       = (const float*)d_in[7];
    const float* W2       = (const float*)d_in[8];
    const float* b2       = (const float*)d_in[9];
    float* out = (float*)d_out;

    char* w = (char*)d_ws;
    size_t off = 0;
    auto alloc = [&](size_t bytes) {
        void* p = w + off;
        off = (off + bytes + 255) & ~(size_t)255;
        return p;
    };
    f16*   xA     = (f16*)alloc((size_t)N_NODES * FDIM * 2);     // 25.6 MB
    f16*   xB     = (f16*)alloc((size_t)N_NODES * FDIM * 2);     // 25.6 MB
    f16*   ybuf   = xB;                                          // alias (xB free)
    int*   histG  = (int*)alloc((size_t)NB * NPART * 4);         // 800 KB
    int*   pstart = (int*)alloc((size_t)(NPART + 1) * 4);
    int*   nstart = (int*)alloc((size_t)N_NODES * 4);
    int*   ncnt   = (int*)alloc((size_t)N_NODES * 4);
    float* dinv   = (float*)alloc((size_t)N_NODES * 4);
    f16*   W0T    = (f16*)alloc(16384 * 2);
    f16*   W1T    = (f16*)alloc(16384 * 2);
    uint2* recs   = (uint2*)alloc((size_t)N_EDGES * 8);          // 12.8 MB

    k1_build<<<NB + GATHER_BLOCKS + 128, 256, 0, stream>>>(
        node_ids, emb, xA, e_dst, histG, W0, W1, W0T, W1T);
    k2a_scan<<<1, 1024, 0, stream>>>(histG, pstart);
    k2b_seed<<<(NPART + 3) / 4, 256, 0, stream>>>(histG, pstart);
    k3_scatter<<<NB, 256, 0, stream>>>(e_src, e_dst, edge_w, histG, recs);
    k4_repack<<<NPART, 256, 0, stream>>>(recs, pstart, nstart, ncnt, dinv);

    int gblocks = (N_NODES + 63) / 64;
    // layer 0:  z = A.x0 ; x1 = leaky(z W0 + b0)
    aggK <<<N_NODES / 4, 256, 0, stream>>>(xA, dinv, nstart, ncnt, recs, xB);
    gemmF<<<gblocks, 256, 0, stream>>>(xB, W0T, b0, xA, N_NODES);
    // layer 1
    aggK <<<N_NODES / 4, 256, 0, stream>>>(xA, dinv, nstart, ncnt, recs, xB);
    gemmF<<<gblocks, 256, 0, stream>>>(xB, W1T, b1, xA, N_NODES);
    // layer 2:  y = x2 W2 (padded) ; out = LSM(A.y + b2)
    gemm20p<<<N_NODES / 32, 256, 0, stream>>>(xA, W2, ybuf);
    agg20L <<<N_NODES / 4, 256, 0, stream>>>(ybuf, dinv, nstart, ncnt, recs, b2, out);
}

// Round 9
// 452.704 us; speedup vs baseline: 1.2908x; 1.0163x over previous
//
#include <hip/hip_runtime.h>
#include <math.h>

typedef _Float16 f16;
typedef _Float16 h8  __attribute__((ext_vector_type(8)));
typedef _Float16 h4  __attribute__((ext_vector_type(4)));
typedef _Float16 h2v __attribute__((ext_vector_type(2)));
typedef float    f4  __attribute__((ext_vector_type(4)));

#define N_NODES 100000
#define N_EDGES 1600000
#define FDIM    128
#define CDIM    20
#define NEG_SLOPE 0.01f

#define NPART 782                    // partitions of 128 dst nodes
#define NB    256                    // histogram/scatter blocks
#define EPB   (N_EDGES / NB)         // 6250 edges per block
#define PBUF  2944                   // repack LDS capacity (mean 2046, +20 sigma)
#define GATHER_BLOCKS (N_NODES * 32 / 256)   // 12500

// ---------------------------------------------------------------------------
// K1 (fused): [0,NB) per-block dst-partition histograms (LDS atomics);
// [NB, NB+GATHER) emb-row gather fp32->fp16; last 128 blocks transpose W0/W1.
// ---------------------------------------------------------------------------
__global__ __launch_bounds__(256) void k1_build(const int* __restrict__ ids,
                                                const float* __restrict__ emb,
                                                f16* __restrict__ X,
                                                const int* __restrict__ dst,
                                                int* __restrict__ histG,
                                                const float* __restrict__ W0,
                                                const float* __restrict__ W1,
                                                f16* __restrict__ W0T,
                                                f16* __restrict__ W1T) {
    int b = blockIdx.x, t = threadIdx.x;
    if (b < NB) {
        __shared__ unsigned lh[NPART];
        for (int i = t; i < NPART; i += 256) lh[i] = 0;
        __syncthreads();
        int e0 = b * EPB;
        for (int i = t; i < EPB; i += 256)
            atomicAdd(&lh[dst[e0 + i] >> 7], 1u);
        __syncthreads();
        for (int i = t; i < NPART; i += 256) histG[b * NPART + i] = (int)lh[i];
    } else if (b < NB + GATHER_BLOCKS) {
        int gid = (b - NB) * 256 + t;                 // N*32 exact
        int n = gid >> 5, qq = gid & 31;
        int v = ids[n];
        float4 vv = ((const float4*)emb)[(size_t)v * 32 + qq];
        h4 o; o[0] = (f16)vv.x; o[1] = (f16)vv.y; o[2] = (f16)vv.z; o[3] = (f16)vv.w;
        ((h4*)X)[(size_t)n * 32 + qq] = o;
    } else {
        int o = (b - NB - GATHER_BLOCKS) * 256 + t;   // 32768 total
        const float* W = (o < 16384) ? W0 : W1;
        f16* T = (o < 16384) ? W0T : W1T;
        int o2 = o & 16383;
        int n = o2 >> 7, k = o2 & 127;
        T[o2] = (f16)W[k * 128 + n];
    }
}

// ---------------------------------------------------------------------------
// K2a: one block: column totals + LDS Hillis-Steele scan -> pstart[0..NPART].
// ---------------------------------------------------------------------------
__global__ __launch_bounds__(1024) void k2a_scan(const int* __restrict__ histG,
                                                 int* __restrict__ pstart) {
    __shared__ int a[1024], bb[1024];
    int t = threadIdx.x;
    int s = 0;
    if (t < NPART)
        for (int b = 0; b < NB; ++b) s += histG[b * NPART + t];
    a[t] = s;
    __syncthreads();
    int* cur = a; int* nxt = bb;
    for (int off = 1; off < 1024; off <<= 1) {
        int v = cur[t] + ((t >= off) ? cur[t - off] : 0);
        nxt[t] = v;
        __syncthreads();
        int* tmp = cur; cur = nxt; nxt = tmp;
    }
    if (t < NPART) pstart[t] = cur[t] - s;            // exclusive
    if (t == NPART - 1) pstart[NPART] = cur[t];
}

// ---------------------------------------------------------------------------
// K2b: one wave per partition: scan the 256 per-block counts -> seed offsets.
// ---------------------------------------------------------------------------
__global__ __launch_bounds__(256) void k2b_seed(int* __restrict__ histG,
                                                const int* __restrict__ pstart) {
    int w = blockIdx.x * 4 + (threadIdx.x >> 6);
    if (w >= NPART) return;
    int lane = threadIdx.x & 63;
    int base = pstart[w];
    int v[4], pre[4], s = 0;
    #pragma unroll
    for (int i = 0; i < 4; ++i) v[i] = histG[(lane * 4 + i) * NPART + w];
    #pragma unroll
    for (int i = 0; i < 4; ++i) { pre[i] = s; s += v[i]; }
    int ss = s;
    #pragma unroll
    for (int off = 1; off < 64; off <<= 1) {
        int u = __shfl_up(ss, off);
        if (lane >= off) ss += u;
    }
    int wexcl = ss - s;
    #pragma unroll
    for (int i = 0; i < 4; ++i)
        histG[(lane * 4 + i) * NPART + w] = base + wexcl + pre[i];
}

// ---------------------------------------------------------------------------
// K3: deterministic scatter via LDS cursors seeded from exact offsets.
//   rec = ((dl<<17)|src, ew_f32)
// ---------------------------------------------------------------------------
__global__ __launch_bounds__(256) void k3_scatter(const int* __restrict__ src,
                                                  const int* __restrict__ dst,
                                                  const float* __restrict__ ew,
                                                  const int* __restrict__ histG,
                                                  uint2* __restrict__ recs) {
    __shared__ unsigned cur[NPART];
    int b = blockIdx.x, t = threadIdx.x;
    for (int i = t; i < NPART; i += 256) cur[i] = (unsigned)histG[b * NPART + i];
    __syncthreads();
    int e0 = b * EPB;
    for (int i = t; i < EPB; i += 256) {
        int e = e0 + i;
        int s = src[e], d = dst[e];
        int p = d >> 7, dl = d & 127;
        unsigned pos = atomicAdd(&cur[p], 1u);        // LDS atomic only
        uint2 r; r.x = ((unsigned)dl << 17) | (unsigned)s; r.y = __float_as_uint(ew[e]);
        recs[pos] = r;
    }
}

// ---------------------------------------------------------------------------
// K4: per-partition repack: sort records by dst_local in LDS, emit
// nstart/ncnt, weighted degree -> dinv. Strips dl from rec.x.
// ---------------------------------------------------------------------------
__global__ __launch_bounds__(256) void k4_repack(uint2* __restrict__ recs,
                                                 const int* __restrict__ pstart,
                                                 int* __restrict__ nstart,
                                                 int* __restrict__ ncnt,
                                                 float* __restrict__ dinv) {
    __shared__ uint2    buf[PBUF];                    // 23.5 KB
    __shared__ float    wsum[128];
    __shared__ unsigned hcnt[128], pref[128], cur[128];
    int p = blockIdx.x, t = threadIdx.x;
    if (t < 128) { hcnt[t] = 0; wsum[t] = 0.f; }
    __syncthreads();
    int base = pstart[p];
    int c = pstart[p + 1] - base;
    if (c > PBUF) c = PBUF;
    for (int i = t; i < c; i += 256) {
        uint2 r = recs[base + i];
        buf[i] = r;
        int dl = r.x >> 17;
        atomicAdd(&hcnt[dl], 1u);
        atomicAdd(&wsum[dl], __uint_as_float(r.y));
    }
    __syncthreads();
    if (t == 0) {
        unsigned s = 0;
        for (int k = 0; k < 128; ++k) { pref[k] = s; s += hcnt[k]; }
    }
    __syncthreads();
    if (t < 128) {
        cur[t] = pref[t];
        int g = p * 128 + t;
        if (g < N_NODES) {
            nstart[g] = base + (int)pref[t];
            ncnt[g]   = (int)hcnt[t];
            dinv[g]   = rsqrtf(wsum[t] + 1.0f);
        }
    }
    __syncthreads();
    for (int i = t; i < c; i += 256) {
        uint2 r = buf[i];
        int dl = r.x >> 17;
        unsigned pos = atomicAdd(&cur[dl], 1u);
        uint2 o; o.x = r.x & 0x1FFFFu; o.y = r.y;
        recs[base + pos] = o;
    }
}

// ---------------------------------------------------------------------------
// aggK: z[n] = dn*(sum dinv[s]*ew*x[s]) + dn^2*x[n].  Wave per node, 8 edges
// per batch (group g of 8 lanes = edge st+j+g; lane loads 32B of the row).
// Loads are UNCONDITIONAL (index clamped to c-1, coef zeroed for overhang)
// so the compiler can software-pipeline gathers across batches — R8's
// conditional loads blocked cross-batch MLP (71us, VALU 49%, HBM 40%).
// ---------------------------------------------------------------------------
__global__ __launch_bounds__(256) void aggK(const f16* __restrict__ Xi,
                                            const float* __restrict__ dinv,
                                            const int* __restrict__ nstart,
                                            const int* __restrict__ ncnt,
                                            const uint2* __restrict__ recs,
                                            f16* __restrict__ Zo) {
    int wave = threadIdx.x >> 6, lane = threadIdx.x & 63;
    int g = lane >> 3, l7 = lane & 7;
    int node = blockIdx.x * 4 + wave;                 // N/4 blocks exact
    int st = nstart[node], c = ncnt[node];
    float acc[16];
    #pragma unroll
    for (int k = 0; k < 16; ++k) acc[k] = 0.f;

    #pragma unroll 2
    for (int j = 0; j < c; j += 8) {
        int jj = j + g;
        int idx = st + (jj < c ? jj : c - 1);         // always valid
        uint2 r = recs[idx];                          // unconditional
        float cf = dinv[r.x] * __uint_as_float(r.y);
        float cc = (jj < c) ? cf : 0.f;
        const f16* rp = Xi + (size_t)r.x * 128 + l7 * 16;
        h8 h0 = *(const h8*)rp;                       // unconditional
        h8 h1 = *(const h8*)(rp + 8);
        #pragma unroll
        for (int k = 0; k < 8; ++k) acc[k]     += cc * (float)h0[k];
        #pragma unroll
        for (int k = 0; k < 8; ++k) acc[k + 8] += cc * (float)h1[k];
    }
    #pragma unroll
    for (int k = 0; k < 16; ++k) {
        acc[k] += __shfl_xor(acc[k], 8);
        acc[k] += __shfl_xor(acc[k], 16);
        acc[k] += __shfl_xor(acc[k], 32);
    }
    float dn = dinv[node], d2 = dn * dn;
    const f16* sp = Xi + (size_t)node * 128 + l7 * 16;
    h8 s0 = *(const h8*)sp;
    h8 s1 = *(const h8*)(sp + 8);
    if (g == 0) {
        h8 o0, o1;
        #pragma unroll
        for (int k = 0; k < 8; ++k) o0[k] = (f16)(dn * acc[k]     + d2 * (float)s0[k]);
        #pragma unroll
        for (int k = 0; k < 8; ++k) o1[k] = (f16)(dn * acc[k + 8] + d2 * (float)s1[k]);
        f16* zp = Zo + (size_t)node * 128 + l7 * 16;
        *(h8*)zp = o0;
        *(h8*)(zp + 8) = o1;
    }
}

// ---------------------------------------------------------------------------
// gemmF: X = leaky(Z @ W + b), fp16 MFMA 16x16x32; 64 rows/block, 4 waves.
// ---------------------------------------------------------------------------
#define GP 136
__global__ __launch_bounds__(256) void gemmF(const f16* __restrict__ Z,
                                             const f16* __restrict__ WT,
                                             const float* __restrict__ bias,
                                             f16* __restrict__ X,
                                             int nrows) {
    __shared__ f16 Xs[64 * GP];
    __shared__ f16 Ws[128 * GP];
    __shared__ float Lb[128];
    int t = threadIdx.x;
    size_t rbase = (size_t)blockIdx.x * 64;

    #pragma unroll
    for (int i = 0; i < 4; ++i) {
        int c = t + 256 * i; int r = c >> 4, c8 = c & 15;
        h8 val = {};
        if (rbase + r < (size_t)nrows)
            val = *(const h8*)(Z + (rbase + r) * 128 + c8 * 8);
        *(h8*)(Xs + r * GP + c8 * 8) = val;
    }
    #pragma unroll
    for (int i = 0; i < 8; ++i) {
        int c = t + 256 * i; int nn = c >> 4, c8 = c & 15;
        *(h8*)(Ws + nn * GP + c8 * 8) = *(const h8*)(WT + nn * 128 + c8 * 8);
    }
    if (t < 128) Lb[t] = bias[t];
    __syncthreads();

    int wave = t >> 6, lane = t & 63, quad = lane >> 4, l15 = lane & 15;
    int m0 = wave * 16;
    f4 acc[8];
    f4 zero = {0.f, 0.f, 0.f, 0.f};
    #pragma unroll
    for (int i = 0; i < 8; ++i) acc[i] = zero;

    #pragma unroll
    for (int kk = 0; kk < 128; kk += 32) {
        h8 a = *(h8*)(Xs + (m0 + l15) * GP + kk + quad * 8);
        #pragma unroll
        for (int nt = 0; nt < 8; ++nt) {
            h8 bf = *(h8*)(Ws + (nt * 16 + l15) * GP + kk + quad * 8);
            acc[nt] = __builtin_amdgcn_mfma_f32_16x16x32_f16(a, bf, acc[nt], 0, 0, 0);
        }
    }
    #pragma unroll
    for (int nt = 0; nt < 8; ++nt) {
        float bb = Lb[nt * 16 + l15];
        #pragma unroll
        for (int r = 0; r < 4; ++r) {
            size_t row = rbase + m0 + quad * 4 + r;
            if (row < (size_t)nrows) {
                float v = acc[nt][r] + bb;
                v = v > 0.f ? v : NEG_SLOPE * v;
                X[row * 128 + nt * 16 + l15] = (f16)v;
            }
        }
    }
}

// ---------------------------------------------------------------------------
// gemm20p: Y = X @ W2 (128 -> 20), fp16 out, padded to stride 32.
// ---------------------------------------------------------------------------
__global__ __launch_bounds__(256) void gemm20p(const f16* __restrict__ X,
                                               const float* __restrict__ W2,
                                               f16* __restrict__ Y) {
    __shared__ f16   Xs[32 * 128];
    __shared__ float Ws[128 * CDIM];
    int t = threadIdx.x;
    const h8* X8 = (const h8*)(X + (size_t)blockIdx.x * 32 * 128);
    ((h8*)Xs)[t]       = X8[t];
    ((h8*)Xs)[t + 256] = X8[t + 256];
    for (int i = t; i < 128 * CDIM; i += 256) Ws[i] = W2[i];
    __syncthreads();
    for (int idx = t; idx < 32 * 32; idx += 256) {
        int r = idx >> 5, cc = idx & 31;
        float acc = 0.f;
        if (cc < CDIM) {
            #pragma unroll 8
            for (int k = 0; k < 128; ++k) acc += (float)Xs[r * 128 + k] * Ws[k * CDIM + cc];
        }
        Y[(size_t)(blockIdx.x * 32 + r) * 32 + cc] = (f16)acc;
    }
}

// ---------------------------------------------------------------------------
// agg20L: out = LSM( b2 + dn*sum(dinv[s]*ew*Y[s]) + dn^2*Y[n] ).  8-edge
// batches with the same unconditional clamped loads; lane loads h4 of the
// padded 64B row; xor(8,16,32) combine; group-local log-softmax.
// ---------------------------------------------------------------------------
__global__ __launch_bounds__(256) void agg20L(const f16* __restrict__ Y,
                                              const float* __restrict__ dinv,
                                              const int* __restrict__ nstart,
                                              const int* __restrict__ ncnt,
                                              const uint2* __restrict__ recs,
                                              const float* __restrict__ b2,
                                              float* __restrict__ out) {
    int wave = threadIdx.x >> 6, lane = threadIdx.x & 63;
    int g = lane >> 3, l7 = lane & 7;
    int node = blockIdx.x * 4 + wave;
    int st = nstart[node], c = ncnt[node];
    float acc[4];
    #pragma unroll
    for (int k = 0; k < 4; ++k) acc[k] = 0.f;

    #pragma unroll 2
    for (int j = 0; j < c; j += 8) {
        int jj = j + g;
        int idx = st + (jj < c ? jj : c - 1);
        uint2 r = recs[idx];
        float cf = dinv[r.x] * __uint_as_float(r.y);
        float cc = (jj < c) ? cf : 0.f;
        h4 hh = *(const h4*)(Y + (size_t)r.x * 32 + l7 * 4);
        #pragma unroll
        for (int k = 0; k < 4; ++k) acc[k] += cc * (float)hh[k];
    }
    #pragma unroll
    for (int k = 0; k < 4; ++k) {
        acc[k] += __shfl_xor(acc[k], 8);
        acc[k] += __shfl_xor(acc[k], 16);
        acc[k] += __shfl_xor(acc[k], 32);
    }
    float dn = dinv[node], d2 = dn * dn;
    h4 hz = *(const h4*)(Y + (size_t)node * 32 + l7 * 4);
    bool live = (l7 < 5);                             // 5 lanes x 4 = 20 classes
    float tv[4];
    float mx = -INFINITY;
    #pragma unroll
    for (int k = 0; k < 4; ++k) {
        tv[k] = live ? (b2[l7 * 4 + k] + dn * acc[k] + d2 * (float)hz[k]) : -INFINITY;
        mx = fmaxf(mx, tv[k]);
    }
    #pragma unroll
    for (int off = 1; off <= 4; off <<= 1) mx = fmaxf(mx, __shfl_xor(mx, off));
    float ex = 0.f;
    if (live) {
        #pragma unroll
        for (int k = 0; k < 4; ++k) ex += expf(tv[k] - mx);
    }
    #pragma unroll
    for (int off = 1; off <= 4; off <<= 1) ex += __shfl_xor(ex, off);
    float ls = logf(ex);
    if (g == 0 && live) {
        float4 o;
        o.x = tv[0] - mx - ls; o.y = tv[1] - mx - ls;
        o.z = tv[2] - mx - ls; o.w = tv[3] - mx - ls;
        *(float4*)(out + (size_t)node * CDIM + l7 * 4) = o;
    }
}

// ---------------------------------------------------------------------------
extern "C" void kernel_launch(void* const* d_in, const int* in_sizes, int n_in,
                              void* d_out, int out_size, void* d_ws, size_t ws_size,
                              hipStream_t stream) {
    (void)in_sizes; (void)n_in; (void)out_size; (void)ws_size;
    const int*   node_ids = (const int*)d_in[0];
    const int*   e_src    = (const int*)d_in[1];
    const int*   e_dst    = e_src + N_EDGES;
    const float* edge_w   = (const float*)d_in[2];
    const float* emb      = (const float*)d_in[3];
    const float* W0       = (const float*)d_in[4];
    const float* b0       = (const float*)d_in[5];
    const float* W1       = (const float*)d_in[6];
    const float* b1       = (const float*)d_in[7];
    const float* W2       = (const float*)d_in[8];
    const float* b2       = (const float*)d_in[9];
    float* out = (float*)d_out;

    char* w = (char*)d_ws;
    size_t off = 0;
    auto alloc = [&](size_t bytes) {
        void* p = w + off;
        off = (off + bytes + 255) & ~(size_t)255;
        return p;
    };
    f16*   xA     = (f16*)alloc((size_t)N_NODES * FDIM * 2);     // 25.6 MB
    f16*   xB     = (f16*)alloc((size_t)N_NODES * FDIM * 2);     // 25.6 MB
    f16*   ybuf   = xB;                                          // alias (xB free)
    int*   histG  = (int*)alloc((size_t)NB * NPART * 4);         // 800 KB
    int*   pstart = (int*)alloc((size_t)(NPART + 1) * 4);
    int*   nstart = (int*)alloc((size_t)N_NODES * 4);
    int*   ncnt   = (int*)alloc((size_t)N_NODES * 4);
    float* dinv   = (float*)alloc((size_t)N_NODES * 4);
    f16*   W0T    = (f16*)alloc(16384 * 2);
    f16*   W1T    = (f16*)alloc(16384 * 2);
    uint2* recs   = (uint2*)alloc((size_t)N_EDGES * 8);          // 12.8 MB

    k1_build<<<NB + GATHER_BLOCKS + 128, 256, 0, stream>>>(
        node_ids, emb, xA, e_dst, histG, W0, W1, W0T, W1T);
    k2a_scan<<<1, 1024, 0, stream>>>(histG, pstart);
    k2b_seed<<<(NPART + 3) / 4, 256, 0, stream>>>(histG, pstart);
    k3_scatter<<<NB, 256, 0, stream>>>(e_src, e_dst, edge_w, histG, recs);
    k4_repack<<<NPART, 256, 0, stream>>>(recs, pstart, nstart, ncnt, dinv);

    int gblocks = (N_NODES + 63) / 64;
    // layer 0:  z = A.x0 ; x1 = leaky(z W0 + b0)
    aggK <<<N_NODES / 4, 256, 0, stream>>>(xA, dinv, nstart, ncnt, recs, xB);
    gemmF<<<gblocks, 256, 0, stream>>>(xB, W0T, b0, xA, N_NODES);
    // layer 1
    aggK <<<N_NODES / 4, 256, 0, stream>>>(xA, dinv, nstart, ncnt, recs, xB);
    gemmF<<<gblocks, 256, 0, stream>>>(xB, W1T, b1, xA, N_NODES);
    // layer 2:  y = x2 W2 (padded) ; out = LSM(A.y + b2)
    gemm20p<<<N_NODES / 32, 256, 0, stream>>>(xA, W2, ybuf);
    agg20L <<<N_NODES / 4, 256, 0, stream>>>(ybuf, dinv, nstart, ncnt, recs, b2, out);
}